// Round 12
// baseline (121.766 us; speedup 1.0000x reference)
//
#include <hip/hip_runtime.h>
#include <math.h>

// out[b,i,j,f] = min_{di,dj,c} ( x[b,i+di,j+dj,c] - W[di,dj,c,f] )
// x: (16,128,128,16) f32, W: (3,3,16,32) f32, out: (16,126,126,32) f32
//
// R25 = R24 with the min tree rebuilt on v_min3_f16 (VALU-rate fix).
// R24 closed the overhead tree (I-fetch null; LDS null; occupancy null;
// spill null). Re-derivation: CDNA vector f16 = f32 FLOPS -> VOP3P packed
// ops are 4 clk/wave64 (2 elem/lane through the 32-wide f32 pipe), not 2.
// Main loop at 4clk: 23 x 69 pk x 4 x 12 waves/SIMD = 31.7us == measured
// 32us busy. The kernel has been AT the packed-f16 VALU roofline since
// R13 -- which is why every structural change nulled.
// Rate asymmetry: v_min3_f16 (VOP3 scalar) = 2 mins/2clk = 2x the min
// throughput of v_pk_min_f16 (2 mins/4clk). Subs are rate-equal in all
// forms (0.5 elem/clk) -> keep pk-subs, replace the whole min tree with
// min3_f16 + op_sel half-addressing, collapsing each weight row's 24
// values straight to scalar. Accs become scalar; final minh disappears.
// Per body: 290 clk -> 220 clk (-24%). Predicted busy 32->25us,
// dur 47->39-42us.
//
// Structure (otherwise R24):
//  * 512-thread blocks, 8 output cols (grid 16x6x16 = 1536 blocks).
//  * W read once via volatile-asm 9x ds_read_b128 (remat-proof, resident).
//  * rolled 10-pair steady loop (I$-resident), preA/preB static parity.
//  * tile + wbuf read-only after ONE staging barrier; vm separate buffer.
//  * full-wave b16 vm writes; float4 merge epilogue (WRITE == out size).

#define TI 21           // output rows per block; 126 = 21*6
#define TROWS (TI + 2)  // input rows per tile (23)
#define NCOL 8          // output cols per block
#define SCOL 10         // staged cols (NCOL + 2 halo)
#define LROW 80         // tile row stride in halves (10 cols * 8 halves)
#define VCOL 68         // vm col stride in halves (64 used + 4 pad)
#define VROW (NCOL * VCOL)  // 544 halves per output row

typedef _Float16 h2 __attribute__((ext_vector_type(2)));

__device__ __forceinline__ h2 hmin2(h2 a, h2 b) {
    return __builtin_elementwise_min(a, b);  // cold paths only
}

// Guaranteed-packed sub (non-volatile: schedulable, CSE/DCE-able)
__device__ __forceinline__ h2 pksub(h2 a, h2 b) {   // a - b, packed
    h2 d;
    asm("v_pk_add_f16 %0, %1, %2 neg_lo:[0,1] neg_hi:[0,1]"
        : "=v"(d) : "v"(a), "v"(b));
    return d;
}
__device__ __forceinline__ _Float16 minh(_Float16 a, _Float16 b) {
    _Float16 d;
    asm("v_min_f16 %0, %1, %2" : "=v"(d) : "v"(a), "v"(b));
    return d;
}
// v_min3_f16 variants: op_sel bit i reads hi-half of src i (dst: lo).
__device__ __forceinline__ _Float16 min3_lhl(h2 a, h2 b, h2 c) {
    _Float16 d;   // min(a.lo, b.hi, c.lo)
    asm("v_min3_f16 %0, %1, %2, %3 op_sel:[0,1,0,0]"
        : "=v"(d) : "v"(a), "v"(b), "v"(c));
    return d;
}
__device__ __forceinline__ _Float16 min3_hlh(h2 a, h2 b, h2 c) {
    _Float16 d;   // min(a.hi, b.lo, c.hi)
    asm("v_min3_f16 %0, %1, %2, %3 op_sel:[1,0,1,0]"
        : "=v"(d) : "v"(a), "v"(b), "v"(c));
    return d;
}
__device__ __forceinline__ _Float16 min3_s(_Float16 a, _Float16 b, _Float16 c) {
    _Float16 d;
    asm("v_min3_f16 %0, %1, %2, %3" : "=v"(d) : "v"(a), "v"(b), "v"(c));
    return d;
}

__device__ __forceinline__ h2 pkrtz(float a, float b) {
    auto r = __builtin_amdgcn_cvt_pkrtz(a, b);  // v_cvt_pkrtz_f16_f32
    return *reinterpret_cast<h2*>(&r);
}

// scalar min over all 24 halves of (pr - w) for one weight row:
// 12 pk-sub (4clk) + 8 mixed min3 + 3 min3 + 1 min (all 2clk).
__device__ __forceinline__ _Float16 rowmin3s(const float4* pr, const h2* w) {
    h2 t[12];
#pragma unroll
    for (int dj = 0; dj < 3; ++dj) {
        const h2* p = reinterpret_cast<const h2*>(&pr[dj]);
#pragma unroll
        for (int q = 0; q < 4; ++q)
            t[dj * 4 + q] = pksub(p[q], w[dj * 4 + q]);
    }
    _Float16 g0 = min3_lhl(t[0], t[0], t[1]);   // t0L,t0H,t1L
    _Float16 g1 = min3_hlh(t[1], t[2], t[2]);   // t1H,t2L,t2H
    _Float16 g2 = min3_lhl(t[3], t[3], t[4]);
    _Float16 g3 = min3_hlh(t[4], t[5], t[5]);
    _Float16 g4 = min3_lhl(t[6], t[6], t[7]);
    _Float16 g5 = min3_hlh(t[7], t[8], t[8]);
    _Float16 g6 = min3_lhl(t[9], t[9], t[10]);
    _Float16 g7 = min3_hlh(t[10], t[11], t[11]);
    _Float16 h0 = min3_s(g0, g1, g2);
    _Float16 h1 = min3_s(g3, g4, g5);
    _Float16 h2v = min3_s(g6, g7, h0);
    return minh(h1, h2v);
}

__global__ __launch_bounds__(512)
__attribute__((amdgpu_waves_per_eu(4, 4)))
void erosion_kernel(
    const float* __restrict__ x, const float* __restrict__ Wt,
    float* __restrict__ out)
{
    __shared__ __align__(16) _Float16 tile[2 * TROWS * LROW];  // 7360 B
    __shared__ __align__(16) _Float16 wbuf[2 * 2304];          // 9216 B
    __shared__ __align__(16) _Float16 vm[TI * VROW];           // 22848 B

    const int tid = threadIdx.x;
    const int f  = tid & 31;
    const int ch = (tid >> 5) & 1;   // channel half: 0 -> c 0..7, 1 -> c 8..15
    const int jt = tid >> 6;         // column in block 0..7 (wave-uniform)
    const int b  = blockIdx.z;
    const int i0 = blockIdx.y * TI;
    const int jb = blockIdx.x * NCOL;

    // ---- stage x tile: fp32 -> fp16 LDS (23 rows x 10 cols x 2 ch) ----
    if (tid < TROWS * 2 * SCOL) {
        const float* xg = x + (size_t)b * (128 * 128 * 16);
        int r   = tid / (2 * SCOL);
        int k   = tid % (2 * SCOL);
        int cc  = k >> 1;               // 0..9 tile column
        int ch2 = k & 1;
        int col = min(jb + cc, 127);    // clamp: feeds never-stored outputs only
        const float* src = xg + ((size_t)(i0 + r) * 128 + col) * 16 + ch2 * 8;
        float4 lo = *reinterpret_cast<const float4*>(src);
        float4 hi = *reinterpret_cast<const float4*>(src + 4);
        h2 o[4] = { pkrtz(lo.x, lo.y), pkrtz(lo.z, lo.w),
                    pkrtz(hi.x, hi.y), pkrtz(hi.z, hi.w) };
        *reinterpret_cast<float4*>(
            &tile[ch2 * (TROWS * LROW) + r * LROW + cc * 8]) =
            *reinterpret_cast<float4*>(o);
    }

    // ---- stage W packed-h2, TAP-CONTIGUOUS layout ----
    // wl h2-index p*256 + ch*128 + f*4 + q = {W[p, ch*8+2q, f], W[p, ch*8+2q+1, f]}
    {
        h2* wl = reinterpret_cast<h2*>(wbuf);
        auto wstage = [&](int t) {
            int g  = t >> 5;           // p*8 + cpair
            int ff = t & 31;
            int p  = g >> 3;
            int cp = g & 7;            // ch2*4 + q
            int ch2 = cp >> 2;
            int q  = cp & 3;
            wl[p * 256 + ch2 * 128 + ff * 4 + q] =
                pkrtz(Wt[g * 64 + ff], Wt[g * 64 + 32 + ff]);
        };
#pragma unroll
        for (int rr = 0; rr < 4; ++rr) wstage(rr * 512 + tid);
        if (tid < 2304 - 2048) wstage(2048 + tid);
    }

    __syncthreads();   // barrier 1: tile + wbuf read-only from here on

    // ---- read this thread's W frags ONCE via volatile asm (remat-proof,
    // R21-verified resident). 9x ds_read_b128, conflict-free. ----
    float4 w9[9];
    {
        unsigned wa = (unsigned)(uintptr_t)(&wbuf[0]) + ch * 512 + f * 16;
        asm volatile(
            "ds_read_b128 %0, %9 offset:0\n\t"
            "ds_read_b128 %1, %9 offset:1024\n\t"
            "ds_read_b128 %2, %9 offset:2048\n\t"
            "ds_read_b128 %3, %9 offset:3072\n\t"
            "ds_read_b128 %4, %9 offset:4096\n\t"
            "ds_read_b128 %5, %9 offset:5120\n\t"
            "ds_read_b128 %6, %9 offset:6144\n\t"
            "ds_read_b128 %7, %9 offset:7168\n\t"
            "ds_read_b128 %8, %9 offset:8192\n\t"
            "s_waitcnt lgkmcnt(0)"
            : "=&v"(w9[0]), "=&v"(w9[1]), "=&v"(w9[2]), "=&v"(w9[3]),
              "=&v"(w9[4]), "=&v"(w9[5]), "=&v"(w9[6]), "=&v"(w9[7]),
              "=&v"(w9[8])
            : "v"(wa)
            : "memory");
    }
    const h2* wh0 = reinterpret_cast<const h2*>(&w9[0]);  // taps 0..2 (di=0)
    const h2* wh1 = reinterpret_cast<const h2*>(&w9[3]);  // taps 3..5 (di=1)
    const h2* wh2 = reinterpret_cast<const h2*>(&w9[6]);  // taps 6..8 (di=2)

    const _Float16* lb = &tile[ch * (TROWS * LROW) + jt * 8];  // row 0, col jt

    // preA holds even rows, preB odd rows (static indexing in rolled loop)
    float4 preA[3], preB[3];
#pragma unroll
    for (int dj = 0; dj < 3; ++dj) {
        preA[dj] = *reinterpret_cast<const float4*>(lb + 0 * LROW + dj * 8);
        preB[dj] = *reinterpret_cast<const float4*>(lb + 1 * LROW + dj * 8);
    }

    const _Float16 HINF = (_Float16)__builtin_huge_valf();
    _Float16 accB = HINF;  // partial min for output row r-1
    _Float16 accC = HINF;  // partial min for output row r-2

    _Float16* vp = &vm[jt * VCOL + ch * 32 + f];   // output row 0 slot

    // ---- prologue bodies 0,1 (no vm write) ----
    {   // body 0: consume preA(row0), reload preA <- row2
        _Float16 n0 = rowmin3s(preA, wh0);
        _Float16 n1 = rowmin3s(preA, wh1);
        const _Float16* ln = lb + 2 * LROW;
#pragma unroll
        for (int dj = 0; dj < 3; ++dj)
            preA[dj] = *reinterpret_cast<const float4*>(ln + dj * 8);
        accC = n1;     // accB=+inf
        accB = n0;
        // body0's wh2 term belongs to output row -2: never computed (DCE'd)
    }
    {   // body 1: consume preB(row1), reload preB <- row3
        _Float16 n0 = rowmin3s(preB, wh0);
        _Float16 n1 = rowmin3s(preB, wh1);
        const _Float16* ln = lb + 3 * LROW;
#pragma unroll
        for (int dj = 0; dj < 3; ++dj)
            preB[dj] = *reinterpret_cast<const float4*>(ln + dj * 8);
        accC = minh(accB, n1);   // row0 partial: min(body0.n0, body1.n1)
        accB = n0;
    }

    // ---- rolled steady loop: 10 pairs = bodies 2..21 ----
    const _Float16* ldp = lb + 4 * LROW;   // pair r loads rows r+2, r+3
#pragma clang loop unroll(disable)
    for (int it = 0; it < 10; ++it) {
        {   // even body r = 2 + 2*it: consume preA(row r), load row r+2
            _Float16 n0 = rowmin3s(preA, wh0);
            _Float16 n1 = rowmin3s(preA, wh1);
            _Float16 n2 = rowmin3s(preA, wh2);
#pragma unroll
            for (int dj = 0; dj < 3; ++dj)
                preA[dj] = *reinterpret_cast<const float4*>(ldp + dj * 8);
            _Float16 fin2 = minh(accC, n2);   // output row r-2 done
            accC = minh(accB, n1);
            accB = n0;
            vp[0] = fin2;
        }
        {   // odd body r+1: consume preB(row r+1), load row r+3
            _Float16 n0 = rowmin3s(preB, wh0);
            _Float16 n1 = rowmin3s(preB, wh1);
            _Float16 n2 = rowmin3s(preB, wh2);
            const _Float16* ln = ldp + LROW;
#pragma unroll
            for (int dj = 0; dj < 3; ++dj)
                preB[dj] = *reinterpret_cast<const float4*>(ln + dj * 8);
            _Float16 fin2 = minh(accC, n2);   // output row r-1 done
            accC = minh(accB, n1);
            accB = n0;
            vp[VROW] = fin2;
        }
        ldp += 2 * LROW;
        vp  += 2 * VROW;
    }
    // (pair it=9 loads rows 22 and "23": row 23 read lands inside the LDS
    //  block (wbuf region), value never consumed -- harmless.)

    // ---- tail body 22: consume preA(row22), only the wh2 term is live ----
    {
        _Float16 n2 = rowmin3s(preA, wh2);
        _Float16 fin2 = minh(accC, n2);   // output row 20 complete
        vp[0] = fin2;
    }

    __syncthreads();   // barrier 2: vm complete

    // ---- merge epilogue: 1344 float4 tasks, 1KB contiguous per wave ----
    {
        float* outb = out + (size_t)b * (126 * 126 * 32);
        auto merge = [&](int t) {
            int row = t >> 6;
            int k   = t & 63;
            int col = k >> 3;
            int q   = k & 7;
            int jj  = jb + col;
            const _Float16* base = &vm[row * VROW + col * VCOL + q * 4];
            h2 a[2], c[2];
            *reinterpret_cast<double*>(a) = *reinterpret_cast<const double*>(base);
            *reinterpret_cast<double*>(c) = *reinterpret_cast<const double*>(base + 32);
            h2 m0 = hmin2(a[0], c[0]);
            h2 m1 = hmin2(a[1], c[1]);
            float4 o = { (float)m0[0], (float)m0[1], (float)m1[0], (float)m1[1] };
            if (jj < 126)
                *reinterpret_cast<float4*>(
                    &outb[((size_t)(i0 + row) * 126 + jj) * 32 + q * 4]) = o;
        };
        merge(tid);
        merge(tid + 512);
        if (tid < TI * 64 - 1024) merge(tid + 1024);  // 320 extra tasks
    }
}

extern "C" void kernel_launch(void* const* d_in, const int* in_sizes, int n_in,
                              void* d_out, int out_size, void* d_ws, size_t ws_size,
                              hipStream_t stream) {
    const float* x  = (const float*)d_in[0];  // 16*128*128*16
    const float* Wt = (const float*)d_in[1];  // 3*3*16*32
    float* out = (float*)d_out;               // 16*126*126*32

    dim3 grid(16, 6, 16);   // 1536 blocks, 8 output cols each
    dim3 block(512);
    erosion_kernel<<<grid, block, 0, stream>>>(x, Wt, out);
}

// Round 13
// 115.798 us; speedup vs baseline: 1.0515x; 1.0515x over previous
//
#include <hip/hip_runtime.h>
#include <math.h>

// out[b,i,j,f] = min_{di,dj,c} ( x[b,i+di,j+dj,c] - W[di,dj,c,f] )
// x: (16,128,128,16) f32, W: (3,3,16,32) f32, out: (16,126,126,32) f32
//
// R26 = f32 + v_min3_f32 compute core (rate fix with measured footing).
// R25 post-mortem: min3_f16/op_sel regressed (busy 32->46us): half-register
// extraction movs / slow f16-VOP3. Model stands: VOP3P pk-f16 = 4clk
// (CDNA vector f16 = f32 rate) -> f16-pk floor ~30us busy, we're at 32.
// The only 2x-rate op on this chip is 3-src f32 VOP3: v_fma_f32 measured
// 2clk (m07) -> v_min3_f32 same class. Elem-ops/output = 287:
// f16-pk = 574 clk/64out (29.7us device); f32+min3 = 144 sub + 72 min3
// = 431 clk/64out (22.3us device floor, -30%). f32 has no half-register
// mov hazard (R25's failure mode).
// Restructure: 4-way channel split (4 ch/thread -> W = 36 f32 regs,
// register-safe), 4 output cols/block, grid (32,6,16) = 3072 blocks.
// chq pairs are lanes l/l+32 -> permlane32_swap+fminf merge (R15-proven),
// f16 vm partials, proven float4 epilogue (WRITE == out size).
// Predicted: busy 32->26us, dur 47.3->40-43, VGPR ~85, FETCH ~10MB.
// Falsifier: dur >= 46 -> at the 2-input-op VALU floor -> roofline.

#define TI 21           // output rows per block; 126 = 21*6
#define TROWS (TI + 2)  // input rows per tile (23)
#define NCOL 4          // output cols per block
#define SCOL 6          // staged cols (NCOL + 2 halo)
#define TROWF 96        // tile row stride in floats (6 cols * 16 ch)
#define WPF 640         // wbuf floats per tap (32 f * 20 padded)
#define VROW 288        // vm halves per output row (4 jt * 2 src * 36)
#define VGRP 36         // vm halves per (jt,src) group (32 + 4 pad)

typedef _Float16 h2 __attribute__((ext_vector_type(2)));

__device__ __forceinline__ h2 hmin2(h2 a, h2 b) {
    return __builtin_elementwise_min(a, b);  // epilogue only
}

// guaranteed 3-input f32 min (VOP3, 2clk class like v_fma_f32 per m07)
__device__ __forceinline__ float min3f(float a, float b, float c) {
    float d;
    asm("v_min3_f32 %0, %1, %2, %3" : "=v"(d) : "v"(a), "v"(b), "v"(c));
    return d;
}

// min over 12 f32 of (pr - w) for one weight row di:
// 12 v_sub_f32 + 5 v_min3_f32 + 1 v_min_f32.
__device__ __forceinline__ float rowminf(const float4* pr, const float4* w) {
    float s[12];
#pragma unroll
    for (int dj = 0; dj < 3; ++dj) {
        const float* p = reinterpret_cast<const float*>(&pr[dj]);
        const float* q = reinterpret_cast<const float*>(&w[dj]);
#pragma unroll
        for (int j = 0; j < 4; ++j)
            s[dj * 4 + j] = p[j] - q[j];
    }
    float g0 = min3f(s[0], s[1], s[2]);
    float g1 = min3f(s[3], s[4], s[5]);
    float g2 = min3f(s[6], s[7], s[8]);
    float g3 = min3f(s[9], s[10], s[11]);
    return fminf(min3f(g0, g1, g2), g3);
}

// merge chq-pair partials across lanes l/l+32: min(own, partner).
__device__ __forceinline__ float mergev(float v) {
    unsigned u = __builtin_bit_cast(unsigned, v);
#if __has_builtin(__builtin_amdgcn_permlane32_swap)
    auto sw = __builtin_amdgcn_permlane32_swap(u, u, false, false);
    return fminf(__builtin_bit_cast(float, (unsigned)sw[0]),
                 __builtin_bit_cast(float, (unsigned)sw[1]));
#else
    unsigned ub = (unsigned)__shfl_xor((int)u, 32, 64);
    return fminf(v, __builtin_bit_cast(float, ub));
#endif
}

__global__ __launch_bounds__(512)
__attribute__((amdgpu_waves_per_eu(4, 4)))
void erosion_kernel(
    const float* __restrict__ x, const float* __restrict__ Wt,
    float* __restrict__ out)
{
    __shared__ __align__(16) float    tileF[TROWS * TROWF];  //  8832 B
    __shared__ __align__(16) float    wbufF[9 * WPF];        // 23040 B
    __shared__ __align__(16) _Float16 vm[TI * VROW];         // 12096 B

    const int tid = threadIdx.x;
    const int f   = tid & 31;
    const int chq = (tid >> 5) & 3;   // channel quarter: 4 ch each
    const int jt  = tid >> 7;         // column in block 0..3
    const int src = (tid >> 6) & 1;   // wave parity: chq{0,1} vs {2,3}
    const int b  = blockIdx.z;
    const int i0 = blockIdx.y * TI;
    const int jb = blockIdx.x * NCOL;

    // ---- stage x tile f32 (no cvt): 23 rows x 6 cols x 16 ch ----
    // 552 float4 chunks (one 4-ch group each).
    {
        const float* xg = x + (size_t)b * (128 * 128 * 16);
        auto stage = [&](int t) {
            int r  = t / 24;
            int k  = t % 24;
            int cc = k >> 2;               // 0..5 tile column
            int cg = k & 3;                // 4-ch group
            int col = min(jb + cc, 127);   // clamp: feeds never-stored cols only
            const float* s = xg + ((size_t)(i0 + r) * 128 + col) * 16 + cg * 4;
            *reinterpret_cast<float4*>(&tileF[r * TROWF + cc * 16 + cg * 4]) =
                *reinterpret_cast<const float4*>(s);
        };
        stage(tid);
        if (tid < TROWS * 24 - 512) stage(512 + tid);  // 40 extra
    }

    // ---- stage W transposed: wbufF[p][f][c] (f-stride 20, 16B-aligned
    // per f so the 9 b128 thread-reads are legal). 9 coalesced rounds. ----
    {
#pragma unroll
        for (int rr = 0; rr < 9; ++rr) {
            int idx = rr * 512 + tid;           // = p*512 + c*32 + ff
            int p  = idx >> 9;
            int c  = (idx >> 5) & 15;
            int ff = idx & 31;
            wbufF[p * WPF + ff * 20 + c] = Wt[idx];
        }
    }

    __syncthreads();   // the only staging barrier

    // ---- read this thread's 36 W floats ONCE via volatile asm:
    // 9x ds_read_b128 (remat-proof, R21-proven technique). ----
    float4 w9[9];
    {
        unsigned wa = (unsigned)(uintptr_t)(&wbufF[0]) + f * 80 + chq * 16;
        asm volatile(
            "ds_read_b128 %0, %9 offset:0\n\t"
            "ds_read_b128 %1, %9 offset:2560\n\t"
            "ds_read_b128 %2, %9 offset:5120\n\t"
            "ds_read_b128 %3, %9 offset:7680\n\t"
            "ds_read_b128 %4, %9 offset:10240\n\t"
            "ds_read_b128 %5, %9 offset:12800\n\t"
            "ds_read_b128 %6, %9 offset:15360\n\t"
            "ds_read_b128 %7, %9 offset:17920\n\t"
            "ds_read_b128 %8, %9 offset:20480\n\t"
            "s_waitcnt lgkmcnt(0)"
            : "=&v"(w9[0]), "=&v"(w9[1]), "=&v"(w9[2]), "=&v"(w9[3]),
              "=&v"(w9[4]), "=&v"(w9[5]), "=&v"(w9[6]), "=&v"(w9[7]),
              "=&v"(w9[8])
            : "v"(wa)
            : "memory");
    }

    // per-thread tile base: row 0, col jt, channels chq*4..+3
    const float* t0 = tileF + jt * 16 + chq * 4;

    // preA holds even rows, preB odd rows (static parity, rolled loop)
    float4 preA[3], preB[3];
#pragma unroll
    for (int dj = 0; dj < 3; ++dj) {
        preA[dj] = *reinterpret_cast<const float4*>(t0 + 0 * TROWF + dj * 16);
        preB[dj] = *reinterpret_cast<const float4*>(t0 + 1 * TROWF + dj * 16);
    }

    const float FINF = __builtin_huge_valf();
    float accB = FINF;  // partial min for output row r-1
    float accC = FINF;  // partial min for output row r-2

    _Float16* vp = &vm[jt * (2 * VGRP) + src * VGRP + f];  // out row 0 slot

    // ---- prologue bodies 0,1 (no vm write) ----
    {   // body 0: consume preA(row0), reload preA <- row2
        float n0 = rowminf(preA, &w9[0]);
        float n1 = rowminf(preA, &w9[3]);
        const float* ln = t0 + 2 * TROWF;
#pragma unroll
        for (int dj = 0; dj < 3; ++dj)
            preA[dj] = *reinterpret_cast<const float4*>(ln + dj * 16);
        accC = n1;     // accB was +inf
        accB = n0;
    }
    {   // body 1: consume preB(row1), reload preB <- row3
        float n0 = rowminf(preB, &w9[0]);
        float n1 = rowminf(preB, &w9[3]);
        const float* ln = t0 + 3 * TROWF;
#pragma unroll
        for (int dj = 0; dj < 3; ++dj)
            preB[dj] = *reinterpret_cast<const float4*>(ln + dj * 16);
        accC = fminf(accB, n1);   // row0 partial
        accB = n0;
    }

    // ---- rolled steady loop: 10 pairs = bodies 2..21 ----
    const float* ldp = t0 + 4 * TROWF;   // pair loads rows r+2, r+3
#pragma clang loop unroll(disable)
    for (int it = 0; it < 10; ++it) {
        {   // even body r = 2+2it: consume preA(row r), load row r+2
            float n0 = rowminf(preA, &w9[0]);
            float n1 = rowminf(preA, &w9[3]);
            float n2 = rowminf(preA, &w9[6]);
#pragma unroll
            for (int dj = 0; dj < 3; ++dj)
                preA[dj] = *reinterpret_cast<const float4*>(ldp + dj * 16);
            float fin2 = fminf(accC, n2);     // output row r-2 done
            accC = fminf(accB, n1);
            accB = n0;
            vp[0] = (_Float16)mergev(fin2);   // lanes l,l+32 write same value
        }
        {   // odd body r+1: consume preB(row r+1), load row r+3
            float n0 = rowminf(preB, &w9[0]);
            float n1 = rowminf(preB, &w9[3]);
            float n2 = rowminf(preB, &w9[6]);
            const float* ln = ldp + TROWF;
#pragma unroll
            for (int dj = 0; dj < 3; ++dj)
                preB[dj] = *reinterpret_cast<const float4*>(ln + dj * 16);
            float fin2 = fminf(accC, n2);     // output row r-1 done
            accC = fminf(accB, n1);
            accB = n0;
            vp[VROW] = (_Float16)mergev(fin2);
        }
        ldp += 2 * TROWF;
        vp  += 2 * VROW;
    }
    // (pair it=9 loads rows 22 and "23": row-23 read lands in wbufF region
    //  -- inside the block's LDS, value never consumed, harmless.)

    // ---- tail body 22: only the di=2 term is live ----
    {
        float n2 = rowminf(preA, &w9[6]);
        float fin2 = fminf(accC, n2);         // output row 20 complete
        vp[0] = (_Float16)mergev(fin2);
    }

    __syncthreads();   // vm complete

    // ---- merge epilogue: 672 float4 tasks, 1KB contiguous per wave ----
    // task t: row = t>>5, k = t&31, col = k>>3 (0..3), q = k&7.
    // partials: src0 at vm[row*288 + col*72 + 4q..+3], src1 at +36.
    {
        float* outb = out + (size_t)b * (126 * 126 * 32);
        auto merge = [&](int t) {
            int row = t >> 5;
            int k   = t & 31;
            int col = k >> 3;
            int q   = k & 7;
            int jj  = jb + col;
            const _Float16* base = &vm[row * VROW + col * (2 * VGRP) + q * 4];
            h2 a[2], c[2];
            *reinterpret_cast<double*>(a) = *reinterpret_cast<const double*>(base);
            *reinterpret_cast<double*>(c) = *reinterpret_cast<const double*>(base + VGRP);
            h2 m0 = hmin2(a[0], c[0]);
            h2 m1 = hmin2(a[1], c[1]);
            float4 o = { (float)m0[0], (float)m0[1], (float)m1[0], (float)m1[1] };
            if (jj < 126)
                *reinterpret_cast<float4*>(
                    &outb[((size_t)(i0 + row) * 126 + jj) * 32 + q * 4]) = o;
        };
        merge(tid);
        if (tid < TI * 32 - 512) merge(512 + tid);  // 160 extra tasks
    }
}

extern "C" void kernel_launch(void* const* d_in, const int* in_sizes, int n_in,
                              void* d_out, int out_size, void* d_ws, size_t ws_size,
                              hipStream_t stream) {
    const float* x  = (const float*)d_in[0];  // 16*128*128*16
    const float* Wt = (const float*)d_in[1];  // 3*3*16*32
    float* out = (float*)d_out;               // 16*126*126*32

    dim3 grid(32, 6, 16);   // 3072 blocks, 4 output cols each
    dim3 block(512);
    erosion_kernel<<<grid, block, 0, stream>>>(x, Wt, out);
}

// Round 14
// 109.625 us; speedup vs baseline: 1.1108x; 1.0563x over previous
//
#include <hip/hip_runtime.h>
#include <math.h>

// out[b,i,j,f] = min_{di,dj,c} ( x[b,i+di,j+dj,c] - W[di,dj,c,f] )
// x: (16,128,128,16) f32, W: (3,3,16,32) f32, out: (16,126,126,32) f32
//
// R27 = R24 core + persistent 3-tile blocks with pipelined staging (T14).
// Rate model CLOSED by R22/R25/R26 calibration: ALL min/sub-class VALU
// ops = 4 clk/wave64 on gfx950 (only FMA path is 32-wide; m07's 2clk is
// FMA-only). f16-pk (2 elem/4clk) is the fastest encoding; R26's f32 =
// 1 elem/4clk ran 60us busy (predicted 57). Algebraic floor 287 elem-ops/
// output -> 29.7us busy; R22 measured 32us busy = 93% of pipe. The lever
// left is wall-busy = 15us of serial staging latency + barriers.
// Change: grid (16,2,16)=512 blocks; each block does 3 i0-tiles.
//  * W staged + asm-read ONCE per block (/3 cost).
//  * tile LDS double-buffered; next tile's globals issued via PINNED
//    asm volatile global_load_dwordx4 BEFORE the main loop (can't sink --
//    the R23 collapse), committed (vmcnt(0)+cvt+ds_write) after it.
//    HBM latency hides under ~10us of compute.
//  * 2 barriers per tile (B1: vm done; B2: next buf + vm reuse safe).
// Predicted: VGPR ~85 (stage regs live), dur 47.3 -> 40-44us.
// If null at ~47: gap is irreducible at this grain -> roofline (93%).

#define TI 21           // output rows per tile; 126 = 21*6
#define TROWS (TI + 2)  // input rows per tile (23)
#define NCOL 8          // output cols per block
#define SCOL 10         // staged cols (NCOL + 2 halo)
#define LROW 80         // tile row stride in halves (10 cols * 8 halves)
#define TSIZE (2 * TROWS * LROW)   // halves per tile buffer (3680)
#define VCOL 68         // vm col stride in halves (64 used + 4 pad)
#define VROW (NCOL * VCOL)  // 544 halves per output row

typedef _Float16 h2 __attribute__((ext_vector_type(2)));

__device__ __forceinline__ h2 hmin2(h2 a, h2 b) {
    return __builtin_elementwise_min(a, b);  // cold paths only
}

// Guaranteed-packed ops (non-volatile: schedulable, CSE-able)
__device__ __forceinline__ h2 pksub(h2 a, h2 b) {   // a - b, packed
    h2 d;
    asm("v_pk_add_f16 %0, %1, %2 neg_lo:[0,1] neg_hi:[0,1]"
        : "=v"(d) : "v"(a), "v"(b));
    return d;
}
__device__ __forceinline__ h2 pkmin(h2 a, h2 b) {
    h2 d;
    asm("v_pk_min_f16 %0, %1, %2" : "=v"(d) : "v"(a), "v"(b));
    return d;
}
__device__ __forceinline__ _Float16 minh(_Float16 a, _Float16 b) {
    _Float16 d;
    asm("v_min_f16 %0, %1, %2" : "=v"(d) : "v"(a), "v"(b));
    return d;
}
__device__ __forceinline__ h2 pkrtz(float a, float b) {
    auto r = __builtin_amdgcn_cvt_pkrtz(a, b);  // v_cvt_pkrtz_f16_f32
    return *reinterpret_cast<h2*>(&r);
}

// min over 12 half2 of (pr[k] - w[k]) for one weight row di.
__device__ __forceinline__ h2 rowmin3(const float4* pr, const h2* w) {
    h2 t[12];
#pragma unroll
    for (int dj = 0; dj < 3; ++dj) {
        const h2* p = reinterpret_cast<const h2*>(&pr[dj]);
#pragma unroll
        for (int q = 0; q < 4; ++q)
            t[dj * 4 + q] = pksub(p[q], w[dj * 4 + q]);
    }
#pragma unroll
    for (int k = 0; k < 6; ++k) t[k] = pkmin(t[k], t[k + 6]);
    t[0] = pkmin(t[0], t[3]);
    t[1] = pkmin(t[1], t[4]);
    t[2] = pkmin(t[2], t[5]);
    return pkmin(pkmin(t[0], t[1]), t[2]);
}

__global__ __launch_bounds__(512)
__attribute__((amdgpu_waves_per_eu(4, 4)))
void erosion_kernel(
    const float* __restrict__ x, const float* __restrict__ Wt,
    float* __restrict__ out)
{
    __shared__ __align__(16) _Float16 tile2[2][TSIZE];   // 2 x 7360 B
    __shared__ __align__(16) _Float16 wbuf[2 * 2304];    // 9216 B
    __shared__ __align__(16) _Float16 vm[TI * VROW];     // 22848 B

    const int tid = threadIdx.x;
    const int f  = tid & 31;
    const int ch = (tid >> 5) & 1;   // channel half
    const int jt = tid >> 6;         // column in block 0..7 (wave-uniform)
    const int b  = blockIdx.z;
    const int i0base = blockIdx.y * (3 * TI);   // 0 or 63
    const int jb = blockIdx.x * NCOL;
    const float* xg = x + (size_t)b * (128 * 128 * 16);

    // staging chunk mapping (tid-only, reused every tile)
    const bool stg = tid < TROWS * 2 * SCOL;     // 460 chunks
    const int sr   = tid / (2 * SCOL);           // tile row
    const int sk   = tid % (2 * SCOL);
    const int scc  = sk >> 1;                    // tile column 0..9
    const int sch  = sk & 1;                     // channel half
    const int scol = min(jb + scc, 127);         // clamped image col
    const int sdst = sch * (TROWS * LROW) + sr * LROW + scc * 8;

    // ---- stage tile 0 directly (load+cvt+write, pre-barrier) ----
    if (stg) {
        const float* src = xg + ((size_t)(i0base + sr) * 128 + scol) * 16 + sch * 8;
        float4 lo = *reinterpret_cast<const float4*>(src);
        float4 hi = *reinterpret_cast<const float4*>(src + 4);
        h2 o[4] = { pkrtz(lo.x, lo.y), pkrtz(lo.z, lo.w),
                    pkrtz(hi.x, hi.y), pkrtz(hi.z, hi.w) };
        *reinterpret_cast<float4*>(&tile2[0][sdst]) =
            *reinterpret_cast<float4*>(o);
    }

    // ---- stage W packed-h2, TAP-CONTIGUOUS (once per block) ----
    {
        h2* wl = reinterpret_cast<h2*>(wbuf);
        auto wstage = [&](int t) {
            int g  = t >> 5;
            int ff = t & 31;
            int p  = g >> 3;
            int cp = g & 7;
            int ch2 = cp >> 2;
            int q  = cp & 3;
            wl[p * 256 + ch2 * 128 + ff * 4 + q] =
                pkrtz(Wt[g * 64 + ff], Wt[g * 64 + 32 + ff]);
        };
#pragma unroll
        for (int rr = 0; rr < 4; ++rr) wstage(rr * 512 + tid);
        if (tid < 2304 - 2048) wstage(2048 + tid);
    }

    __syncthreads();   // tile0 + wbuf ready

    // ---- read W frags ONCE via volatile asm (remat-proof) ----
    float4 w9[9];
    {
        unsigned wa = (unsigned)(uintptr_t)(&wbuf[0]) + ch * 512 + f * 16;
        asm volatile(
            "ds_read_b128 %0, %9 offset:0\n\t"
            "ds_read_b128 %1, %9 offset:1024\n\t"
            "ds_read_b128 %2, %9 offset:2048\n\t"
            "ds_read_b128 %3, %9 offset:3072\n\t"
            "ds_read_b128 %4, %9 offset:4096\n\t"
            "ds_read_b128 %5, %9 offset:5120\n\t"
            "ds_read_b128 %6, %9 offset:6144\n\t"
            "ds_read_b128 %7, %9 offset:7168\n\t"
            "ds_read_b128 %8, %9 offset:8192\n\t"
            "s_waitcnt lgkmcnt(0)"
            : "=&v"(w9[0]), "=&v"(w9[1]), "=&v"(w9[2]), "=&v"(w9[3]),
              "=&v"(w9[4]), "=&v"(w9[5]), "=&v"(w9[6]), "=&v"(w9[7]),
              "=&v"(w9[8])
            : "v"(wa)
            : "memory");
    }
    const h2* wh0 = reinterpret_cast<const h2*>(&w9[0]);
    const h2* wh1 = reinterpret_cast<const h2*>(&w9[3]);
    const h2* wh2 = reinterpret_cast<const h2*>(&w9[6]);

    const _Float16 HINF = (_Float16)__builtin_huge_valf();
    float* outb = out + (size_t)b * (126 * 126 * 32);

    for (int t = 0; t < 3; ++t) {
        const _Float16* buf = tile2[t & 1];
        const int i0 = i0base + t * TI;

        // ---- issue next tile's global loads (PINNED: cannot sink) ----
        float4 sl, sh;
        const bool do_next = (t < 2) && stg;
        if (do_next) {
            const float* src =
                xg + ((size_t)(i0 + TI + sr) * 128 + scol) * 16 + sch * 8;
            asm volatile(
                "global_load_dwordx4 %0, %2, off\n\t"
                "global_load_dwordx4 %1, %2, off offset:16"
                : "=&v"(sl), "=&v"(sh)
                : "v"(src)
                : "memory");
        }

        // ---- main loop on buf (R24 rolled structure) ----
        const _Float16* lb = buf + ch * (TROWS * LROW) + jt * 8;
        float4 preA[3], preB[3];
#pragma unroll
        for (int dj = 0; dj < 3; ++dj) {
            preA[dj] = *reinterpret_cast<const float4*>(lb + 0 * LROW + dj * 8);
            preB[dj] = *reinterpret_cast<const float4*>(lb + 1 * LROW + dj * 8);
        }
        h2 accB = {HINF, HINF};
        h2 accC = {HINF, HINF};
        _Float16* vp = &vm[jt * VCOL + ch * 32 + f];

        {   // body 0
            h2 n0 = rowmin3(preA, wh0);
            h2 n1 = rowmin3(preA, wh1);
            const _Float16* ln = lb + 2 * LROW;
#pragma unroll
            for (int dj = 0; dj < 3; ++dj)
                preA[dj] = *reinterpret_cast<const float4*>(ln + dj * 8);
            accC = pkmin(accB, n1);
            accB = n0;
        }
        {   // body 1
            h2 n0 = rowmin3(preB, wh0);
            h2 n1 = rowmin3(preB, wh1);
            const _Float16* ln = lb + 3 * LROW;
#pragma unroll
            for (int dj = 0; dj < 3; ++dj)
                preB[dj] = *reinterpret_cast<const float4*>(ln + dj * 8);
            accC = pkmin(accB, n1);
            accB = n0;
        }
        const _Float16* ldp = lb + 4 * LROW;
#pragma clang loop unroll(disable)
        for (int it = 0; it < 10; ++it) {
            {   // even body
                h2 n0 = rowmin3(preA, wh0);
                h2 n1 = rowmin3(preA, wh1);
                h2 n2 = rowmin3(preA, wh2);
#pragma unroll
                for (int dj = 0; dj < 3; ++dj)
                    preA[dj] = *reinterpret_cast<const float4*>(ldp + dj * 8);
                h2 fin2 = pkmin(accC, n2);
                accC = pkmin(accB, n1);
                accB = n0;
                vp[0] = minh(fin2[0], fin2[1]);
            }
            {   // odd body
                h2 n0 = rowmin3(preB, wh0);
                h2 n1 = rowmin3(preB, wh1);
                h2 n2 = rowmin3(preB, wh2);
                const _Float16* ln = ldp + LROW;
#pragma unroll
                for (int dj = 0; dj < 3; ++dj)
                    preB[dj] = *reinterpret_cast<const float4*>(ln + dj * 8);
                h2 fin2 = pkmin(accC, n2);
                accC = pkmin(accB, n1);
                accB = n0;
                vp[VROW] = minh(fin2[0], fin2[1]);
            }
            ldp += 2 * LROW;
            vp  += 2 * VROW;
        }
        // (it=9 overreads one row past the tile: lands in the other LDS
        //  buffer / wbuf, value never consumed -- harmless.)
        {   // tail body 22: only di=2 term live
            h2 n2 = rowmin3(preA, wh2);
            h2 fin2 = pkmin(accC, n2);
            vp[0] = minh(fin2[0], fin2[1]);
        }

        __syncthreads();   // B1: vm complete

        // ---- commit next tile: wait loads, cvt, write other buffer ----
        if (do_next) {
            asm volatile("s_waitcnt vmcnt(0)" ::: "memory");
            h2 o[4] = { pkrtz(sl.x, sl.y), pkrtz(sl.z, sl.w),
                        pkrtz(sh.x, sh.y), pkrtz(sh.z, sh.w) };
            *reinterpret_cast<float4*>(&tile2[(t + 1) & 1][sdst]) =
                *reinterpret_cast<float4*>(o);
        }

        // ---- merge epilogue: float4 stores (WRITE == out size) ----
        {
            auto merge = [&](int tt) {
                int row = tt >> 6;
                int k   = tt & 63;
                int col = k >> 3;
                int q   = k & 7;
                int jj  = jb + col;
                const _Float16* base = &vm[row * VROW + col * VCOL + q * 4];
                h2 a[2], c[2];
                *reinterpret_cast<double*>(a) =
                    *reinterpret_cast<const double*>(base);
                *reinterpret_cast<double*>(c) =
                    *reinterpret_cast<const double*>(base + 32);
                h2 m0 = hmin2(a[0], c[0]);
                h2 m1 = hmin2(a[1], c[1]);
                float4 o = { (float)m0[0], (float)m0[1],
                             (float)m1[0], (float)m1[1] };
                if (jj < 126)
                    *reinterpret_cast<float4*>(
                        &outb[((size_t)(i0 + row) * 126 + jj) * 32 + q * 4]) = o;
            };
            merge(tid);
            merge(tid + 512);
            if (tid < TI * 64 - 1024) merge(tid + 1024);
        }

        __syncthreads();   // B2: next buf ready, vm reusable
    }
}

extern "C" void kernel_launch(void* const* d_in, const int* in_sizes, int n_in,
                              void* d_out, int out_size, void* d_ws, size_t ws_size,
                              hipStream_t stream) {
    const float* x  = (const float*)d_in[0];  // 16*128*128*16
    const float* Wt = (const float*)d_in[1];  // 3*3*16*32
    float* out = (float*)d_out;               // 16*126*126*32

    dim3 grid(16, 2, 16);   // 512 persistent blocks, 3 tiles each
    dim3 block(512);
    erosion_kernel<<<grid, block, 0, stream>>>(x, Wt, out);
}

// Round 15
// 107.252 us; speedup vs baseline: 1.1353x; 1.0221x over previous
//
#include <hip/hip_runtime.h>
#include <math.h>

// out[b,i,j,f] = min_{di,dj,c} ( x[b,i+di,j+dj,c] - W[di,dj,c,f] )
// x: (16,128,128,16) f32, W: (3,3,16,32) f32, out: (16,126,126,32) f32
//
// R28 = R24 byte-identical except waves_per_eu(6,6) (co-residency test).
// R27 post-mortem: persistent 3-tile blocks regressed (51.5us): 2 blocks/
// CU + per-tile barriers serialized harder. Busy floor is CLOSED:
// 29.7us algebraic (287 elem-ops/output, subs output-unique, min tree
// irreducible), measured 32us busy = 93%, encoding-optimal (R25/R26
// falsified min3-f16 and f32-min3 via the 4clk/wave-instr law).
// Wall 47.3 = busy x 1.45; residual = phase latency (stage/W-read/
// barriers/epilogue) unhidden. UNTESTED axis: co-residency with the
// PINNED-W kernel -- R21-R24 all ran waves_per_eu(4,4) = 2 blocks/CU
// hard cap. (R13's 51%-occupancy 47.9us doesn't count: that was the
// remat-era kernel, LDS-bound at 44us -- different mechanism.)
// Change: waves_per_eu(6,6) -> budget ~84 regs (VGPR 60 fits, no spill
// pressure; w9 asm-pinned so R17-remat impossible), target 24 waves/CU
// = 3 blocks/CU (LDS 39.4KB x 4 <= 160KB not binding).
// Predicted: occupancy 34->55-70%, dur 47.3->40-44 if phase-overlap
// theory holds. PRE-COMMIT: null (46-48) => ROOFLINE declaration next.
//
// Structure (= R24):
//  * 512-thread blocks, 8 output cols (grid 16x6x16 = 1536 blocks).
//  * W read once via volatile-asm 9x ds_read_b128 (remat-proof, resident).
//  * guaranteed-packed pk f16 core (asm, non-volatile).
//  * rolled 10-pair steady loop (I$-resident), preA/preB static parity.
//  * tile + wbuf read-only after ONE staging barrier; vm separate buffer.
//  * full-wave b16 vm writes; float4 merge epilogue (WRITE == out size).

#define TI 21           // output rows per block; 126 = 21*6
#define TROWS (TI + 2)  // input rows per tile (23)
#define NCOL 8          // output cols per block
#define SCOL 10         // staged cols (NCOL + 2 halo)
#define LROW 80         // tile row stride in halves (10 cols * 8 halves)
#define VCOL 68         // vm col stride in halves (64 used + 4 pad)
#define VROW (NCOL * VCOL)  // 544 halves per output row

typedef _Float16 h2 __attribute__((ext_vector_type(2)));

__device__ __forceinline__ h2 hmin2(h2 a, h2 b) {
    return __builtin_elementwise_min(a, b);  // cold paths only
}

// Guaranteed-packed ops (non-volatile: schedulable, CSE-able)
__device__ __forceinline__ h2 pksub(h2 a, h2 b) {   // a - b, packed
    h2 d;
    asm("v_pk_add_f16 %0, %1, %2 neg_lo:[0,1] neg_hi:[0,1]"
        : "=v"(d) : "v"(a), "v"(b));
    return d;
}
__device__ __forceinline__ h2 pkmin(h2 a, h2 b) {
    h2 d;
    asm("v_pk_min_f16 %0, %1, %2" : "=v"(d) : "v"(a), "v"(b));
    return d;
}
__device__ __forceinline__ _Float16 minh(_Float16 a, _Float16 b) {
    _Float16 d;
    asm("v_min_f16 %0, %1, %2" : "=v"(d) : "v"(a), "v"(b));
    return d;
}

__device__ __forceinline__ h2 pkrtz(float a, float b) {
    auto r = __builtin_amdgcn_cvt_pkrtz(a, b);  // v_cvt_pkrtz_f16_f32
    return *reinterpret_cast<h2*>(&r);
}

// min over 12 half2 of (pr[k] - w[k]) for one weight row di.
__device__ __forceinline__ h2 rowmin3(const float4* pr, const h2* w) {
    h2 t[12];
#pragma unroll
    for (int dj = 0; dj < 3; ++dj) {
        const h2* p = reinterpret_cast<const h2*>(&pr[dj]);
#pragma unroll
        for (int q = 0; q < 4; ++q)
            t[dj * 4 + q] = pksub(p[q], w[dj * 4 + q]);
    }
#pragma unroll
    for (int k = 0; k < 6; ++k) t[k] = pkmin(t[k], t[k + 6]);
    t[0] = pkmin(t[0], t[3]);
    t[1] = pkmin(t[1], t[4]);
    t[2] = pkmin(t[2], t[5]);
    return pkmin(pkmin(t[0], t[1]), t[2]);
}

__global__ __launch_bounds__(512)
__attribute__((amdgpu_waves_per_eu(6, 6)))
void erosion_kernel(
    const float* __restrict__ x, const float* __restrict__ Wt,
    float* __restrict__ out)
{
    __shared__ __align__(16) _Float16 tile[2 * TROWS * LROW];  // 7360 B
    __shared__ __align__(16) _Float16 wbuf[2 * 2304];          // 9216 B
    __shared__ __align__(16) _Float16 vm[TI * VROW];           // 22848 B

    const int tid = threadIdx.x;
    const int f  = tid & 31;
    const int ch = (tid >> 5) & 1;   // channel half: 0 -> c 0..7, 1 -> c 8..15
    const int jt = tid >> 6;         // column in block 0..7 (wave-uniform)
    const int b  = blockIdx.z;
    const int i0 = blockIdx.y * TI;
    const int jb = blockIdx.x * NCOL;

    // ---- stage x tile: fp32 -> fp16 LDS (23 rows x 10 cols x 2 ch) ----
    if (tid < TROWS * 2 * SCOL) {
        const float* xg = x + (size_t)b * (128 * 128 * 16);
        int r   = tid / (2 * SCOL);
        int k   = tid % (2 * SCOL);
        int cc  = k >> 1;               // 0..9 tile column
        int ch2 = k & 1;
        int col = min(jb + cc, 127);    // clamp: feeds never-stored outputs only
        const float* src = xg + ((size_t)(i0 + r) * 128 + col) * 16 + ch2 * 8;
        float4 lo = *reinterpret_cast<const float4*>(src);
        float4 hi = *reinterpret_cast<const float4*>(src + 4);
        h2 o[4] = { pkrtz(lo.x, lo.y), pkrtz(lo.z, lo.w),
                    pkrtz(hi.x, hi.y), pkrtz(hi.z, hi.w) };
        *reinterpret_cast<float4*>(
            &tile[ch2 * (TROWS * LROW) + r * LROW + cc * 8]) =
            *reinterpret_cast<float4*>(o);
    }

    // ---- stage W packed-h2, TAP-CONTIGUOUS layout ----
    // wl h2-index p*256 + ch*128 + f*4 + q = {W[p, ch*8+2q, f], W[p, ch*8+2q+1, f]}
    {
        h2* wl = reinterpret_cast<h2*>(wbuf);
        auto wstage = [&](int t) {
            int g  = t >> 5;           // p*8 + cpair
            int ff = t & 31;
            int p  = g >> 3;
            int cp = g & 7;            // ch2*4 + q
            int ch2 = cp >> 2;
            int q  = cp & 3;
            wl[p * 256 + ch2 * 128 + ff * 4 + q] =
                pkrtz(Wt[g * 64 + ff], Wt[g * 64 + 32 + ff]);
        };
#pragma unroll
        for (int rr = 0; rr < 4; ++rr) wstage(rr * 512 + tid);
        if (tid < 2304 - 2048) wstage(2048 + tid);
    }

    __syncthreads();   // barrier 1: tile + wbuf read-only from here on

    // ---- read this thread's W frags ONCE via volatile asm (remat-proof,
    // R21-proven resident). 9x ds_read_b128. ----
    float4 w9[9];
    {
        unsigned wa = (unsigned)(uintptr_t)(&wbuf[0]) + ch * 512 + f * 16;
        asm volatile(
            "ds_read_b128 %0, %9 offset:0\n\t"
            "ds_read_b128 %1, %9 offset:1024\n\t"
            "ds_read_b128 %2, %9 offset:2048\n\t"
            "ds_read_b128 %3, %9 offset:3072\n\t"
            "ds_read_b128 %4, %9 offset:4096\n\t"
            "ds_read_b128 %5, %9 offset:5120\n\t"
            "ds_read_b128 %6, %9 offset:6144\n\t"
            "ds_read_b128 %7, %9 offset:7168\n\t"
            "ds_read_b128 %8, %9 offset:8192\n\t"
            "s_waitcnt lgkmcnt(0)"
            : "=&v"(w9[0]), "=&v"(w9[1]), "=&v"(w9[2]), "=&v"(w9[3]),
              "=&v"(w9[4]), "=&v"(w9[5]), "=&v"(w9[6]), "=&v"(w9[7]),
              "=&v"(w9[8])
            : "v"(wa)
            : "memory");
    }
    const h2* wh0 = reinterpret_cast<const h2*>(&w9[0]);  // taps 0..2 (di=0)
    const h2* wh1 = reinterpret_cast<const h2*>(&w9[3]);  // taps 3..5 (di=1)
    const h2* wh2 = reinterpret_cast<const h2*>(&w9[6]);  // taps 6..8 (di=2)

    const _Float16* lb = &tile[ch * (TROWS * LROW) + jt * 8];  // row 0, col jt

    // preA holds even rows, preB odd rows (static indexing in rolled loop)
    float4 preA[3], preB[3];
#pragma unroll
    for (int dj = 0; dj < 3; ++dj) {
        preA[dj] = *reinterpret_cast<const float4*>(lb + 0 * LROW + dj * 8);
        preB[dj] = *reinterpret_cast<const float4*>(lb + 1 * LROW + dj * 8);
    }

    const _Float16 HINF = (_Float16)__builtin_huge_valf();
    h2 accB = {HINF, HINF};  // partial min for output row r-1
    h2 accC = {HINF, HINF};  // partial min for output row r-2

    _Float16* vp = &vm[jt * VCOL + ch * 32 + f];   // output row 0 slot

    // ---- prologue bodies 0,1 (no vm write) ----
    {   // body 0: consume preA(row0), reload preA <- row2
        h2 n0 = rowmin3(preA, wh0);
        h2 n1 = rowmin3(preA, wh1);
        const _Float16* ln = lb + 2 * LROW;
#pragma unroll
        for (int dj = 0; dj < 3; ++dj)
            preA[dj] = *reinterpret_cast<const float4*>(ln + dj * 8);
        accC = pkmin(accB, n1);   // accB=+inf: accC = n1
        accB = n0;
    }
    {   // body 1: consume preB(row1), reload preB <- row3
        h2 n0 = rowmin3(preB, wh0);
        h2 n1 = rowmin3(preB, wh1);
        const _Float16* ln = lb + 3 * LROW;
#pragma unroll
        for (int dj = 0; dj < 3; ++dj)
            preB[dj] = *reinterpret_cast<const float4*>(ln + dj * 8);
        accC = pkmin(accB, n1);   // row0 partial: min(body0.n0, body1.n1)
        accB = n0;
    }

    // ---- rolled steady loop: 10 pairs = bodies 2..21 ----
    const _Float16* ldp = lb + 4 * LROW;   // pair r loads rows r+2, r+3
#pragma clang loop unroll(disable)
    for (int it = 0; it < 10; ++it) {
        {   // even body r = 2 + 2*it: consume preA(row r), load row r+2
            h2 n0 = rowmin3(preA, wh0);
            h2 n1 = rowmin3(preA, wh1);
            h2 n2 = rowmin3(preA, wh2);
#pragma unroll
            for (int dj = 0; dj < 3; ++dj)
                preA[dj] = *reinterpret_cast<const float4*>(ldp + dj * 8);
            h2 fin2 = pkmin(accC, n2);        // output row r-2 done
            accC = pkmin(accB, n1);
            accB = n0;
            vp[0] = minh(fin2[0], fin2[1]);
        }
        {   // odd body r+1: consume preB(row r+1), load row r+3
            h2 n0 = rowmin3(preB, wh0);
            h2 n1 = rowmin3(preB, wh1);
            h2 n2 = rowmin3(preB, wh2);
            const _Float16* ln = ldp + LROW;
#pragma unroll
            for (int dj = 0; dj < 3; ++dj)
                preB[dj] = *reinterpret_cast<const float4*>(ln + dj * 8);
            h2 fin2 = pkmin(accC, n2);        // output row r-1 done
            accC = pkmin(accB, n1);
            accB = n0;
            vp[VROW] = minh(fin2[0], fin2[1]);
        }
        ldp += 2 * LROW;
        vp  += 2 * VROW;
    }
    // (pair it=9 loads rows 22 and "23": row 23 read lands inside the LDS
    //  block (wbuf region), value never consumed -- harmless.)

    // ---- tail body 22: only the wh2 term is live ----
    {
        h2 n2 = rowmin3(preA, wh2);
        h2 fin2 = pkmin(accC, n2);    // output row 20 complete
        vp[0] = minh(fin2[0], fin2[1]);
    }

    __syncthreads();   // barrier 2: vm complete

    // ---- merge epilogue: 1344 float4 tasks, 1KB contiguous per wave ----
    {
        float* outb = out + (size_t)b * (126 * 126 * 32);
        auto merge = [&](int t) {
            int row = t >> 6;
            int k   = t & 63;
            int col = k >> 3;
            int q   = k & 7;
            int jj  = jb + col;
            const _Float16* base = &vm[row * VROW + col * VCOL + q * 4];
            h2 a[2], c[2];
            *reinterpret_cast<double*>(a) = *reinterpret_cast<const double*>(base);
            *reinterpret_cast<double*>(c) = *reinterpret_cast<const double*>(base + 32);
            h2 m0 = hmin2(a[0], c[0]);
            h2 m1 = hmin2(a[1], c[1]);
            float4 o = { (float)m0[0], (float)m0[1], (float)m1[0], (float)m1[1] };
            if (jj < 126)
                *reinterpret_cast<float4*>(
                    &outb[((size_t)(i0 + row) * 126 + jj) * 32 + q * 4]) = o;
        };
        merge(tid);
        merge(tid + 512);
        if (tid < TI * 64 - 1024) merge(tid + 1024);  // 320 extra tasks
    }
}

extern "C" void kernel_launch(void* const* d_in, const int* in_sizes, int n_in,
                              void* d_out, int out_size, void* d_ws, size_t ws_size,
                              hipStream_t stream) {
    const float* x  = (const float*)d_in[0];  // 16*128*128*16
    const float* Wt = (const float*)d_in[1];  // 3*3*16*32
    float* out = (float*)d_out;               // 16*126*126*32

    dim3 grid(16, 6, 16);   // 1536 blocks, 8 output cols each
    dim3 block(512);
    erosion_kernel<<<grid, block, 0, stream>>>(x, Wt, out);
}